// Round 7
// baseline (359.621 us; speedup 1.0000x reference)
//
#include <hip/hip_runtime.h>

// ConvAttention fused pipeline for MI355X (gfx950), round 6 (r5 + safety fixes; resubmit).
//
// Pipeline (6 dispatches):
//  kprep  : fold BN into pointwise weights; Wmix/beta; out_w -> bf16 hi/lo; zero vsum+lsum
//  kqkv   : depthwise 3x3 + folded BN + 8x8 pointwise; thread=(n,d-pair), aligned float2
//  kvtrans: v bf16 [b,h,n,d] -> vT [b,h,d,n] + V row-sum partials
//  kl     : lsum[b,c,i] = sum_j 2^(S') ; K-frag-stationary, 512 blocks
//  kattn3 : phase-alternating 16-wave block (b, 32i). Produce: per-wave 16j strip,
//           S^T all 8 heads, normalize, in-register mix, swizzled P~ to LDS (128KB).
//           Consume: wave=(o,d-half) PV MFMA from P~ + vT. 160KB dynamic LDS.
//  kout   : [8192,512]x[512,512]^T projection, bf16 MFMA hi/lo 3-product split

#define EPS 1e-5f
#define SCALE2 0.510138584f  // H^-0.5 * log2(e): softmax in base 2

typedef float f32x4 __attribute__((ext_vector_type(4)));
typedef short short8 __attribute__((ext_vector_type(8)));
typedef unsigned short ushort;

#define MFMA16(a, b, c) __builtin_amdgcn_mfma_f32_16x16x32_bf16(a, b, c, 0, 0, 0)

__device__ __forceinline__ unsigned short f2bf(float f) {
  union { float f; unsigned u; } v; v.f = f;
  return (unsigned short)((v.u + 0x7FFFu + ((v.u >> 16) & 1u)) >> 16);
}
__device__ __forceinline__ float bf2f(unsigned short h) {
  union { unsigned u; float f; } v; v.u = ((unsigned)h) << 16;
  return v.f;
}
__device__ __forceinline__ int cvtpk(float lo, float hi) {
  int r;
  asm("v_cvt_pk_bf16_f32 %0, %1, %2" : "=v"(r) : "v"(lo), "v"(hi));
  return r;
}

// ---------------------------------------------------------------- kprep
__global__ __launch_bounds__(256) void kprep(
    const float* __restrict__ dwb, const float* __restrict__ bng,
    const float* __restrict__ bnb, const float* __restrict__ bnm,
    const float* __restrict__ bnv, const float* __restrict__ pww,
    const float* __restrict__ pwb, const float* __restrict__ rew,
    const float* __restrict__ reb, const float* __restrict__ vng,
    const float* __restrict__ vnb, const float* __restrict__ vnm,
    const float* __restrict__ vnv, const float* __restrict__ outw,
    float* __restrict__ smalls, float* __restrict__ vsum,
    float* __restrict__ lsum, ushort* __restrict__ wh,
    ushort* __restrict__ wl) {
  int g = blockIdx.x * 256 + threadIdx.x;
  if (g < 262144) {
    float v = outw[g];
    ushort hi = f2bf(v);
    wh[g] = hi;
    wl[g] = f2bf(v - bf2f(hi));
  }
  if (blockIdx.x >= 1 && blockIdx.x <= 16)
    vsum[(blockIdx.x - 1) * 256 + threadIdx.x] = 0.f;
  if (blockIdx.x >= 17 && blockIdx.x <= 272)
    lsum[(blockIdx.x - 17) * 256 + threadIdx.x] = 0.f;
  if (blockIdx.x == 0) {
    int t = threadIdx.x;
    if (t < 64) {  // Wmix[o][c]
      int o = t >> 3, c = t & 7;
      float s = vng[o] * rsqrtf(vnv[o] + EPS);
      smalls[t] = rew[o * 8 + c] * s;
    }
    if (t < 8) {   // beta[o]
      float s = vng[t] * rsqrtf(vnv[t] + EPS);
      smalls[64 + t] = (reb[t] - vnm[t]) * s + vnb[t];
    }
    if (t < 192) { // pw_eff[p][o][c]
      int p = t >> 6, rem = t & 63, o = rem >> 3, c = rem & 7;
      float s = bng[p * 8 + c] * rsqrtf(bnv[p * 8 + c] + EPS);
      smalls[72 + t] = pww[(p * 8 + o) * 8 + c] * s;
    }
    if (t < 24) {  // pwb_eff[p][o]
      int p = t / 8, o = t & 7;
      float acc = pwb[p * 8 + o];
      for (int c = 0; c < 8; ++c) {
        float s = bng[p * 8 + c] * rsqrtf(bnv[p * 8 + c] + EPS);
        acc += pww[(p * 8 + o) * 8 + c] *
               ((dwb[p * 8 + c] - bnm[p * 8 + c]) * s + bnb[p * 8 + c]);
      }
      smalls[264 + t] = acc;
    }
  }
}

// ---------------------------------------------------------------- kqkv
// thread = (b, n, d-pair dd..dd+1). Aligned float2 for the pair + guarded scalar
// edges; 72 loads -> 48 outputs (vs r4: 72 -> 24). All loads in-bounds.
__global__ __launch_bounds__(256) void kqkv(
    const float* __restrict__ x, const float* __restrict__ dww,
    const float* __restrict__ smalls,
    ushort* __restrict__ qb, ushort* __restrict__ kb,
    ushort* __restrict__ vb) {
  int g = blockIdx.x * 256 + threadIdx.x;
  int dp = g & 31;
  int n = (g >> 5) & 1023;
  int b = g >> 15;
  int dd = dp * 2;
  float m[3][8][2] = {};
  for (int c = 0; c < 8; ++c) {
    float win[3][4];
#pragma unroll
    for (int ky = 0; ky < 3; ++ky) {
      int nn = n - 1 + ky;
      bool vr = (nn >= 0) && (nn < 1024);
      int nnc = nn < 0 ? 0 : (nn > 1023 ? 1023 : nn);
      const float* xp = x + (((b << 10) + nnc) << 9) + c * 64 + dd;
      float e0 = (dd > 0) ? xp[-1] : 0.f;
      float2 v = *(const float2*)xp;
      float e3 = (dd < 62) ? xp[2] : 0.f;
      win[ky][0] = vr ? e0 : 0.f;
      win[ky][1] = vr ? v.x : 0.f;
      win[ky][2] = vr ? v.y : 0.f;
      win[ky][3] = vr ? e3 : 0.f;
    }
#pragma unroll
    for (int p = 0; p < 3; ++p) {
      const float* wp = dww + (p * 8 + c) * 9;
      float a0 = 0.f, a1 = 0.f;
#pragma unroll
      for (int ky = 0; ky < 3; ++ky)
#pragma unroll
        for (int kx = 0; kx < 3; ++kx) {
          float wv = wp[ky * 3 + kx];
          a0 += wv * win[ky][kx];
          a1 += wv * win[ky][kx + 1];
        }
#pragma unroll
      for (int o = 0; o < 8; ++o) {
        float wv = smalls[72 + p * 64 + o * 8 + c];
        m[p][o][0] += wv * a0;
        m[p][o][1] += wv * a1;
      }
    }
  }
#pragma unroll
  for (int o = 0; o < 8; ++o) {
    int base = ((b * 8 + o) * 1024 + n) * 64 + dd;
    float b0 = smalls[264 + o];
    float b1 = smalls[272 + o];
    float b2 = smalls[280 + o];
    *(int*)(qb + base) = cvtpk((m[0][o][0] + b0) * SCALE2, (m[0][o][1] + b0) * SCALE2);
    *(int*)(kb + base) = cvtpk(m[1][o][0] + b1, m[1][o][1] + b1);
    *(int*)(vb + base) = cvtpk(m[2][o][0] + b2, m[2][o][1] + b2);
  }
}

// ---------------------------------------------------------------- kvtrans (+vsum)
__global__ __launch_bounds__(256) void kvtrans(const ushort* __restrict__ vb,
                                               ushort* __restrict__ vt,
                                               float* __restrict__ vsum) {
  __shared__ ushort lds[64 * 65];
  __shared__ float red[256];
  int bh = blockIdx.x >> 4;
  int nt = blockIdx.x & 15;
  int t = threadIdx.x;
  const ushort* src = vb + (bh * 1024 + nt * 64) * 64;
  float part = 0.f;
#pragma unroll
  for (int it = 0; it < 16; ++it) {
    int nn = (t >> 6) + it * 4;
    int d = t & 63;
    ushort v = src[nn * 64 + d];
    part += bf2f(v);
    lds[nn * 65 + d] = v;
  }
  red[t] = part;
  __syncthreads();
  ushort* dst = vt + bh * 64 * 1024 + nt * 64;
#pragma unroll
  for (int it = 0; it < 16; ++it) {
    int d = (t >> 6) + it * 4;
    int n = t & 63;
    dst[d * 1024 + n] = lds[n * 65 + d];
  }
  if (t < 64)
    atomicAdd(&vsum[bh * 64 + t],
              red[t] + red[64 + t] + red[128 + t] + red[192 + t]);
}

// ---------------------------------------------------------------- kl
// lsum[b,c,i] = sum_j 2^(q_i . k_j). Block = (b, c, j-eighth of 128); 4 waves x 32j.
__global__ __launch_bounds__(256) void kl(const ushort* __restrict__ qb,
                                          const ushort* __restrict__ kb,
                                          float* __restrict__ lsum) {
  __shared__ float lacc[4][1024];
  int b = blockIdx.x & 7;
  int c = (blockIdx.x >> 3) & 7;
  int jq = blockIdx.x >> 6;
  int tid = threadIdx.x;
  int w = tid >> 6, l = tid & 63;
  int lrow = l & 15, lgrp = l >> 4;
#pragma unroll
  for (int e = 0; e < 16; ++e) ((float*)lacc)[tid + e * 256] = 0.f;
  __syncthreads();
  const ushort* kh = kb + ((b * 8 + c) * 1024 + jq * 128 + w * 32) * 64;
  short8 Kf[2][2];
#pragma unroll
  for (int jf = 0; jf < 2; ++jf)
#pragma unroll
    for (int kc = 0; kc < 2; ++kc)
      Kf[jf][kc] = *(const short8*)(kh + (jf * 16 + lrow) * 64 + kc * 32 + lgrp * 8);
  const ushort* qh = qb + (b * 8 + c) * 65536;
  for (int ci = 0; ci < 64; ++ci) {
    f32x4 a0 = {}, a1 = {};
#pragma unroll
    for (int kc = 0; kc < 2; ++kc) {
      short8 Qf = *(const short8*)(qh + (ci * 16 + lrow) * 64 + kc * 32 + lgrp * 8);
      a0 = MFMA16(Kf[0][kc], Qf, a0);
      a1 = MFMA16(Kf[1][kc], Qf, a1);
    }
    float s = 0.f;
#pragma unroll
    for (int r = 0; r < 4; ++r) s += exp2f(a0[r]) + exp2f(a1[r]);
    s += __shfl_xor(s, 16);
    s += __shfl_xor(s, 32);
    if (lgrp == 0) lacc[w][ci * 16 + lrow] += s;
  }
  __syncthreads();
#pragma unroll
  for (int e = 0; e < 4; ++e) {
    int i = tid + e * 256;
    atomicAdd(&lsum[(b * 8 + c) * 1024 + i],
              lacc[0][i] + lacc[1][i] + lacc[2][i] + lacc[3][i]);
  }
}

// ---------------------------------------------------------------- kattn3
// Block = (b, 32i), 16 waves, grid 256 (1 block/CU). Chunk = 256j, 4 chunks.
// Produce: wave w -> j strip [t*256 + w*16, +16), S^T = MFMA(K,Q) per head,
//   p = 2^S * linv, mix over c in-register, pack bf16 -> swizzled plds.
// Consume: wave (o=w>>1, dh=w&1): A from plds, B from vt, 32 MFMA/chunk.
// NOTE: __launch_bounds__(1024,4) is REQUIRED: a 1024-thread block needs <=128
// VGPR/wave to fit 16 waves. unroll caps keep live ranges under that.
__global__ __launch_bounds__(1024, 4) void kattn3(
    const ushort* __restrict__ qb, const ushort* __restrict__ kb,
    const ushort* __restrict__ vt, const float* __restrict__ smalls,
    const float* __restrict__ vsum, const float* __restrict__ lsum,
    ushort* __restrict__ ohi, ushort* __restrict__ olo) {
  extern __shared__ char dyn[];
  ushort* qlds = (ushort*)dyn;             // [8c][32i][64d], 32KB, swz (i&7)<<3
  ushort* plds = (ushort*)(dyn + 32768);   // [8o][32i][256j], 128KB, swz (i&7)<<3
  int b = blockIdx.x & 7;
  int it = blockIdx.x >> 3;
  int i0 = it * 32;
  int tid = threadIdx.x;
  int w = tid >> 6, l = tid & 63;
  int lrow = l & 15, lgrp = l >> 4;

  // stage Q (16 elems per thread)
  {
    int e = tid * 16;
    int c = e >> 11, i = (e >> 6) & 31, d0 = e & 63;
    const ushort* src = qb + ((b * 8 + c) * 1024 + i0 + i) * 64 + d0;
    int sw = (i & 7) << 3;
    *(short8*)&qlds[c * 2048 + i * 64 + (d0 ^ sw)] = *(const short8*)src;
    *(short8*)&qlds[c * 2048 + i * 64 + ((d0 + 8) ^ sw)] = *(const short8*)(src + 8);
  }

  float Wc[64];
#pragma unroll
  for (int z = 0; z < 64; ++z)
    Wc[z] = __builtin_bit_cast(
        float, __builtin_amdgcn_readfirstlane(
                   __builtin_bit_cast(int, smalls[z])));

  float linv[8][2];
#pragma unroll
  for (int c = 0; c < 8; ++c)
#pragma unroll
    for (int if2 = 0; if2 < 2; ++if2)
      linv[c][if2] = 1.0f / lsum[(b * 8 + c) * 1024 + i0 + if2 * 16 + lrow];

  int o = w >> 1, dh = w & 1;
  f32x4 Oacc[2][2] = {};
  __syncthreads();

  for (int t = 0; t < 4; ++t) {
    int jw = t * 256 + w * 16;  // global j of this wave's produce strip
    // ---- produce ----
#pragma unroll 1
    for (int if2 = 0; if2 < 2; ++if2) {
      int irow = if2 * 16 + lrow;
      int qoff = (irow & 7) << 3;
      float m[8][4];
#pragma unroll 2
      for (int c = 0; c < 8; ++c) {
        f32x4 acc = {};
#pragma unroll
        for (int kc = 0; kc < 2; ++kc) {
          short8 Kf = *(const short8*)(kb + ((b * 8 + c) * 1024 + jw + lrow) * 64 +
                                       kc * 32 + lgrp * 8);
          short8 Qf = *(const short8*)&qlds[c * 2048 + irow * 64 +
                                            ((kc * 32 + lgrp * 8) ^ qoff)];
          acc = MFMA16(Kf, Qf, acc);
        }
        float pe[4];
#pragma unroll
        for (int r = 0; r < 4; ++r) pe[r] = exp2f(acc[r]) * linv[c][if2];
#pragma unroll
        for (int o2 = 0; o2 < 8; ++o2) {
          float wv = Wc[o2 * 8 + c];
#pragma unroll
          for (int r = 0; r < 4; ++r) {
            if (c == 0) m[o2][r] = wv * pe[r];
            else        m[o2][r] += wv * pe[r];
          }
        }
      }
      int jslot = ((w * 16 + lgrp * 4) ^ qoff);  // swz bits 3-5 by irow&7
#pragma unroll
      for (int o2 = 0; o2 < 8; ++o2) {
        int w0 = cvtpk(m[o2][0], m[o2][1]);
        int w1 = cvtpk(m[o2][2], m[o2][3]);
        *(int2*)&plds[o2 * 8192 + irow * 256 + jslot] = (int2){w0, w1};
      }
    }
    __syncthreads();
    // ---- consume chunk t ----
#pragma unroll 2
    for (int kc = 0; kc < 8; ++kc) {
      short8 Af[2];
#pragma unroll
      for (int if2 = 0; if2 < 2; ++if2) {
        int irow = if2 * 16 + lrow;
        Af[if2] = *(const short8*)&plds[o * 8192 + irow * 256 +
                                        ((kc * 32 + lgrp * 8) ^ ((irow & 7) << 3))];
      }
#pragma unroll
      for (int df = 0; df < 2; ++df) {
        int drow = dh * 32 + df * 16 + lrow;
        short8 Vf = *(const short8*)(vt + ((b * 8 + o) * 64 + drow) * 1024 +
                                     t * 256 + kc * 32 + lgrp * 8);
#pragma unroll
        for (int if2 = 0; if2 < 2; ++if2)
          Oacc[if2][df] = MFMA16(Af[if2], Vf, Oacc[if2][df]);
      }
    }
    __syncthreads();
  }

  // ---- epilogue: rank-1 beta*Vsum + write O hi/lo ----
  float beta = smalls[64 + o];
#pragma unroll
  for (int if2 = 0; if2 < 2; ++if2)
#pragma unroll
    for (int df = 0; df < 2; ++df) {
      int dcol = dh * 32 + df * 16 + lrow;
      float bv = beta * vsum[(b * 8 + o) * 64 + dcol];
#pragma unroll
      for (int r = 0; r < 4; ++r) {
        int i = i0 + if2 * 16 + lgrp * 4 + r;
        float s = Oacc[if2][df][r] + bv;
        int idx = (b * 1024 + i) * 512 + o * 64 + dcol;
        ushort hi = f2bf(s);
        ohi[idx] = hi;
        olo[idx] = f2bf(s - bf2f(hi));
      }
    }
}

// ---------------------------------------------------------------- kout
__global__ __launch_bounds__(256) void kout(
    const ushort* __restrict__ ohi, const ushort* __restrict__ olo,
    const ushort* __restrict__ wh, const ushort* __restrict__ wl,
    const float* __restrict__ outb, float* __restrict__ out) {
  int w = threadIdx.x >> 6, l = threadIdx.x & 63;
  int lrow = l & 15, lgrp = l >> 4;
  int i0 = blockIdx.x * 128 + w * 32;
  int n0 = blockIdx.y * 64;
  f32x4 acc[2][4] = {};
  for (int kc = 0; kc < 16; ++kc) {
    short8 Ah[2], Al[2], Bh[4], Bl[4];
#pragma unroll
    for (int a = 0; a < 2; ++a) {
      int ro = (i0 + a * 16 + lrow) * 512 + kc * 32 + lgrp * 8;
      Ah[a] = *(const short8*)(ohi + ro);
      Al[a] = *(const short8*)(olo + ro);
    }
#pragma unroll
    for (int nq = 0; nq < 4; ++nq) {
      int ro = (n0 + nq * 16 + lrow) * 512 + kc * 32 + lgrp * 8;
      Bh[nq] = *(const short8*)(wh + ro);
      Bl[nq] = *(const short8*)(wl + ro);
    }
#pragma unroll
    for (int a = 0; a < 2; ++a)
#pragma unroll
      for (int nq = 0; nq < 4; ++nq) {
        acc[a][nq] = MFMA16(Ah[a], Bh[nq], acc[a][nq]);
        acc[a][nq] = MFMA16(Ah[a], Bl[nq], acc[a][nq]);
        acc[a][nq] = MFMA16(Al[a], Bh[nq], acc[a][nq]);
      }
  }
#pragma unroll
  for (int a = 0; a < 2; ++a)
#pragma unroll
    for (int nq = 0; nq < 4; ++nq)
#pragma unroll
      for (int r = 0; r < 4; ++r) {
        int row = i0 + a * 16 + lgrp * 4 + r;
        int n = n0 + nq * 16 + lrow;
        out[row * 512 + n] = acc[a][nq][r] + outb[n];
      }
}

// ---------------------------------------------------------------- launch
extern "C" void kernel_launch(void* const* d_in, const int* in_sizes, int n_in,
                              void* d_out, int out_size, void* d_ws, size_t ws_size,
                              hipStream_t stream) {
  const float* x   = (const float*)d_in[0];
  const float* dww = (const float*)d_in[1];
  const float* dwb = (const float*)d_in[2];
  const float* bng = (const float*)d_in[3];
  const float* bnb = (const float*)d_in[4];
  const float* bnm = (const float*)d_in[5];
  const float* bnv = (const float*)d_in[6];
  const float* pww = (const float*)d_in[7];
  const float* pwb = (const float*)d_in[8];
  const float* rew = (const float*)d_in[9];
  const float* reb = (const float*)d_in[10];
  const float* vng = (const float*)d_in[11];
  const float* vnb = (const float*)d_in[12];
  const float* vnm = (const float*)d_in[13];
  const float* vnv = (const float*)d_in[14];
  const float* outw = (const float*)d_in[15];
  const float* outb = (const float*)d_in[16];

  char* ws = (char*)d_ws;
  const size_t MB = 1024 * 1024;
  ushort* qb  = (ushort*)(ws);
  ushort* kb  = (ushort*)(ws + 8 * MB);
  ushort* vt  = (ushort*)(ws + 16 * MB);
  ushort* vb  = (ushort*)(ws + 24 * MB);
  ushort* ohi = (ushort*)(ws + 32 * MB);
  ushort* olo = (ushort*)(ws + 40 * MB);
  ushort* wh  = (ushort*)(ws + 48 * MB);
  ushort* wl  = (ushort*)(ws + 48 * MB + 512 * 1024);
  float* smalls = (float*)(ws + 49 * MB);
  float* vsum   = (float*)(ws + 49 * MB + 4096);
  float* lsum   = (float*)(ws + 49 * MB + 24576);

  hipFuncSetAttribute((const void*)kattn3,
                      hipFuncAttributeMaxDynamicSharedMemorySize, 163840);

  hipLaunchKernelGGL(kprep, dim3(1024), dim3(256), 0, stream,
                     dwb, bng, bnb, bnm, bnv, pww, pwb, rew, reb, vng, vnb,
                     vnm, vnv, outw, smalls, vsum, lsum, wh, wl);
  hipLaunchKernelGGL(kqkv, dim3(1024), dim3(256), 0, stream,
                     x, dww, smalls, qb, kb, vb);
  hipLaunchKernelGGL(kvtrans, dim3(1024), dim3(256), 0, stream, vb, vt, vsum);
  hipLaunchKernelGGL(kl, dim3(512), dim3(256), 0, stream, qb, kb, lsum);
  hipLaunchKernelGGL(kattn3, dim3(256), dim3(1024), 163840, stream,
                     qb, kb, vt, smalls, vsum, lsum, ohi, olo);
  hipLaunchKernelGGL(kout, dim3(64, 8), dim3(256), 0, stream,
                     ohi, olo, wh, wl, outb, (float*)d_out);
}